// Round 2
// baseline (359.531 us; speedup 1.0000x reference)
//
#include <hip/hip_runtime.h>

constexpr int LMAX = 8;
constexpr int NCOL = (LMAX + 1) * (LMAX + 1);   // 81
constexpr int PTS  = 64;                         // points per block (one wave)
constexpr int HALF = 32;                         // points per store phase
constexpr int PHASE_FLOATS = HALF * NCOL;        // 2592 floats = 10368 B

__device__ __forceinline__ void emit_col(float (&res)[NCOL], const float* __restrict__ F,
                                         int l, int m, float Q, float sm, float cm) {
    const int fbase = l * (l + 1) / 2;
    const int cbase = l * l + l;
    if (m == 0) {
        const float inv_sqrt2 = 0.70710678118654752440f;
        res[cbase] = F[fbase] * Q * inv_sqrt2;
    } else {
        float t = F[fbase + m] * Q;
        res[cbase - m] = t * sm;
        res[cbase + m] = t * cm;
    }
}

__global__ __launch_bounds__(PTS, 4) void sh_kernel(const float* __restrict__ xyz,
                                                    const float* __restrict__ F,
                                                    float* __restrict__ out, int n) {
    __shared__ float tile[PHASE_FLOATS];   // 10368 B
    const int lane    = threadIdx.x;
    const int base_pt = blockIdx.x * PTS;
    const int i       = base_pt + lane;

    float x = 0.0f, y = 0.0f, z = 1.0f;
    if (i < n) {
        x = xyz[3 * i + 0];
        y = xyz[3 * i + 1];
        z = xyz[3 * i + 2];
    }
    const float rsq  = x * x + y * y + z * z;
    const float rinv = rsqrtf(rsq);
    x *= rinv; y *= rinv; z *= rinv;

    float res[NCOL];

    float Qmm = 1.0f;           // Q[m,m]
    float sm = 0.0f, cm = 1.0f; // s[m], c[m]

#pragma unroll
    for (int m = 0; m <= LMAX; ++m) {
        if (m > 0) {
            Qmm = -(float)(2 * m - 1) * Qmm;
            const float s_new = x * sm + y * cm;
            const float c_new = x * cm - y * sm;
            sm = s_new; cm = c_new;
        }
        // l = m
        float Qp = Qmm;
        emit_col(res, F, m, m, Qp, sm, cm);
        if (m < LMAX) {
            // l = m+1 : Q[m+1,m] = (2m+1) * z * Q[m,m]
            float Qc = (float)(2 * m + 1) * z * Qmm;
            emit_col(res, F, m + 1, m, Qc, sm, cm);
#pragma unroll
            for (int l = m + 2; l <= LMAX; ++l) {
                const float Qn = ((float)(2 * l - 1) * z * Qc
                                  - (float)(l + m - 1) * Qp) * (1.0f / (float)(l - m));
                Qp = Qc; Qc = Qn;
                emit_col(res, F, l, m, Qc, sm, cm);
            }
        }
    }

    const long long lim = (long long)n * NCOL;

#pragma unroll
    for (int ph = 0; ph < 2; ++ph) {
        __syncthreads();   // protect LDS reuse across phases (cheap: 1-wave block)
        const int sel = lane - ph * HALF;
        if (sel >= 0 && sel < HALF) {
            float* row = &tile[sel * NCOL];
#pragma unroll
            for (int k = 0; k < 20; ++k) {
                float4 v = make_float4(res[4 * k + 0], res[4 * k + 1],
                                       res[4 * k + 2], res[4 * k + 3]);
                *(float4*)(row + 4 * k) = v;
            }
            row[80] = res[80];
        }
        __syncthreads();

        const long long off = (long long)base_pt * NCOL + (long long)ph * PHASE_FLOATS;
        if (base_pt + PTS <= n) {
            // off is a multiple of 2592 floats -> 16B aligned
            float4* dst       = (float4*)(out + off);
            const float4* src = (const float4*)tile;
#pragma unroll
            for (int k = 0; k < 10; ++k) {
                dst[k * PTS + lane] = src[k * PTS + lane];
            }
            if (lane < 8) dst[10 * PTS + lane] = src[10 * PTS + lane];  // 648 = 640 + 8
        } else {
            for (int k = lane; k < PHASE_FLOATS; k += PTS) {
                const long long gi = off + k;
                if (gi < lim) out[gi] = tile[k];
            }
        }
    }
}

extern "C" void kernel_launch(void* const* d_in, const int* in_sizes, int n_in,
                              void* d_out, int out_size, void* d_ws, size_t ws_size,
                              hipStream_t stream) {
    const float* xyz = (const float*)d_in[0];
    const float* F   = (const float*)d_in[1];
    float* out       = (float*)d_out;
    const int n      = in_sizes[0] / 3;
    const int grid   = (n + PTS - 1) / PTS;
    sh_kernel<<<grid, PTS, 0, stream>>>(xyz, F, out, n);
}